// Round 2
// baseline (3078.369 us; speedup 1.0000x reference)
//
#include <hip/hip_runtime.h>
#include <math.h>

#define TOK 16384
#define HD 7168
#define NE 256

constexpr int BM = 128, BN = 128, BK = 32, PAD = 4;
constexpr int NTHR = 256;
constexpr int NKC = HD / BK;      // 224 chunks of 32 k
constexpr int NSPLIT = 3;         // split-K: 75/75/74 chunks -> 768 blocks = 3/CU

// fp32 GEMM with split-K=3. Accuracy scheme (unchanged from R1, proven):
// fp32 FMA within a BK=32 chunk, chunk sums accumulated in f64. Split partials
// combined with f64 atomics (reassociation noise ~1e-15, cannot flip top-k).
__global__ __launch_bounds__(256, 3)
void gemm_logits(const float* __restrict__ A, const float* __restrict__ W,
                 double* __restrict__ L64) {
  __shared__ __align__(16) float sa[BK][BM + PAD];
  __shared__ __align__(16) float sb[BK][BN + PAD];

  const int tid = threadIdx.x;
  const int bid = blockIdx.x;
  const int z    = bid % NSPLIT;
  const int tile = bid / NSPLIT;
  const int bm = tile >> 1;   // 128 row-blocks
  const int bn = tile & 1;    // 2 col-blocks
  const int tx = tid & 15;    // expert quad
  const int ty = tid >> 4;    // token quad

  const int kc0 = z * 75;
  const int kcN = (z == 2) ? (NKC - 150) : 75;   // 75/75/74

  // per-thread staging geometry, precomputed once
  const float* aP[4];
  const float* wP[4];
  int srow[4], scol[4];
#pragma unroll
  for (int p = 0; p < 4; ++p) {
    int id = tid + p * NTHR;
    int row = id >> 3, c4 = id & 7;
    srow[p] = row;
    scol[p] = c4 * 4;
    aP[p] = A + (size_t)(bm * BM + row) * HD + kc0 * BK + c4 * 4;
    wP[p] = W + (size_t)(bn * BN + row) * HD + kc0 * BK + c4 * 4;
  }

  float4 ra[4], rb[4];
#pragma unroll
  for (int p = 0; p < 4; ++p) {
    ra[p] = *(const float4*)aP[p];
    rb[p] = *(const float4*)wP[p];
    aP[p] += BK;
    wP[p] += BK;
  }

  float  accf[2][2][4][4];
  double accd[2][2][4][4];
#pragma unroll
  for (int p = 0; p < 2; ++p)
#pragma unroll
    for (int q = 0; q < 2; ++q)
#pragma unroll
      for (int i = 0; i < 4; ++i)
#pragma unroll
        for (int j = 0; j < 4; ++j) {
          accf[p][q][i][j] = 0.f;
          accd[p][q][i][j] = 0.0;
        }

  for (int kc = 0; kc < kcN; ++kc) {
    __syncthreads();
#pragma unroll
    for (int p = 0; p < 4; ++p) {
      sa[scol[p] + 0][srow[p]] = ra[p].x;
      sa[scol[p] + 1][srow[p]] = ra[p].y;
      sa[scol[p] + 2][srow[p]] = ra[p].z;
      sa[scol[p] + 3][srow[p]] = ra[p].w;
      sb[scol[p] + 0][srow[p]] = rb[p].x;
      sb[scol[p] + 1][srow[p]] = rb[p].y;
      sb[scol[p] + 2][srow[p]] = rb[p].z;
      sb[scol[p] + 3][srow[p]] = rb[p].w;
    }
    __syncthreads();
    if (kc + 1 < kcN) {
#pragma unroll
      for (int p = 0; p < 4; ++p) {
        ra[p] = *(const float4*)aP[p];
        rb[p] = *(const float4*)wP[p];
        aP[p] += BK;
        wP[p] += BK;
      }
    }
#pragma unroll 8
    for (int kk = 0; kk < BK; ++kk) {
      float4 a0 = *(const float4*)&sa[kk][ty * 4];
      float4 a1 = *(const float4*)&sa[kk][64 + ty * 4];
      float4 b0 = *(const float4*)&sb[kk][tx * 4];
      float4 b1 = *(const float4*)&sb[kk][64 + tx * 4];
      float am[2][4] = {{a0.x, a0.y, a0.z, a0.w}, {a1.x, a1.y, a1.z, a1.w}};
      float bv[2][4] = {{b0.x, b0.y, b0.z, b0.w}, {b1.x, b1.y, b1.z, b1.w}};
#pragma unroll
      for (int qm = 0; qm < 2; ++qm)
#pragma unroll
        for (int qn = 0; qn < 2; ++qn)
#pragma unroll
          for (int i = 0; i < 4; ++i)
#pragma unroll
            for (int j = 0; j < 4; ++j)
              accf[qm][qn][i][j] = fmaf(am[qm][i], bv[qn][j], accf[qm][qn][i][j]);
    }
#pragma unroll
    for (int qm = 0; qm < 2; ++qm)
#pragma unroll
      for (int qn = 0; qn < 2; ++qn)
#pragma unroll
        for (int i = 0; i < 4; ++i)
#pragma unroll
          for (int j = 0; j < 4; ++j) {
            accd[qm][qn][i][j] += (double)accf[qm][qn][i][j];
            accf[qm][qn][i][j] = 0.f;
          }
  }

  // epilogue: combine split-K partials with f64 atomics
  double* lBase = L64 + (size_t)(bm * BM) * NE + bn * BN;
#pragma unroll
  for (int qm = 0; qm < 2; ++qm)
#pragma unroll
    for (int i = 0; i < 4; ++i) {
      int row = qm * 64 + ty * 4 + i;
#pragma unroll
      for (int qn = 0; qn < 2; ++qn)
#pragma unroll
        for (int j = 0; j < 4; ++j) {
#if defined(__AMDGCN__)
          unsafeAtomicAdd(lBase + (size_t)row * NE + qn * 64 + tx * 4 + j,
                          accd[qm][qn][i][j]);
#else
          atomicAdd(lBase + (size_t)row * NE + qn * 64 + tx * 4 + j,
                    accd[qm][qn][i][j]);
#endif
        }
    }
}

// One wave per token. Selection semantics bit-identical to R1: cast logits to
// fp32 first, then f64 sigmoid / f64 group sums / repeated wave argmax.
__global__ __launch_bounds__(256)
void router(const double* __restrict__ L64, float* __restrict__ out_w,
            float* __restrict__ out_i, float* __restrict__ logitsO) {
  const int gid = blockIdx.x * blockDim.x + threadIdx.x;
  const int tok = gid >> 6;
  const int lane = gid & 63;
  if (tok >= TOK) return;

  const double* lp = L64 + (size_t)tok * NE + lane * 4;
  const double l0 = lp[0], l1 = lp[1], l2 = lp[2], l3 = lp[3];
  const float f0 = (float)l0, f1 = (float)l1, f2 = (float)l2, f3 = (float)l3;
  // fp32 logits output
  *(float4*)(logitsO + (size_t)tok * NE + lane * 4) = make_float4(f0, f1, f2, f3);

  double s[4];
  s[0] = 1.0 / (1.0 + exp(-(double)f0));
  s[1] = 1.0 / (1.0 + exp(-(double)f1));
  s[2] = 1.0 / (1.0 + exp(-(double)f2));
  s[3] = 1.0 / (1.0 + exp(-(double)f3));

  // group sums: lanes [8g..8g+7] cover experts [32g..32g+31]
  double gsum = s[0] + s[1] + s[2] + s[3];
  gsum += __shfl_xor(gsum, 1);
  gsum += __shfl_xor(gsum, 2);
  gsum += __shfl_xor(gsum, 4);

  double gs[8];
#pragma unroll
  for (int g = 0; g < 8; ++g) gs[g] = __shfl(gsum, g * 8);

  // top-4 groups (ties -> lower index)
  unsigned sel = 0;
#pragma unroll
  for (int r = 0; r < 4; ++r) {
    int best = 0;
    double bvv = -1e300;
#pragma unroll
    for (int g = 0; g < 8; ++g)
      if (!((sel >> g) & 1) && gs[g] > bvv) {
        bvv = gs[g];
        best = g;
      }
    sel |= 1u << best;
  }

  const int grp = lane >> 3;
  const bool act = (sel >> grp) & 1;
  double ms[4];
#pragma unroll
  for (int j = 0; j < 4; ++j) ms[j] = act ? s[j] : -1.0;

  // top-8 experts by repeated wave argmax
  double vals[8];
  int idxs[8];
#pragma unroll
  for (int r = 0; r < 8; ++r) {
    double lv = -3.0;
    int li = 1 << 30;
#pragma unroll
    for (int j = 0; j < 4; ++j)
      if (ms[j] > lv) {
        lv = ms[j];
        li = lane * 4 + j;
      }
#pragma unroll
    for (int off = 1; off < 64; off <<= 1) {
      double ov = __shfl_xor(lv, off);
      int oi = __shfl_xor(li, off);
      if (ov > lv || (ov == lv && oi < li)) {
        lv = ov;
        li = oi;
      }
    }
    vals[r] = lv;
    idxs[r] = li;
    if ((li >> 2) == lane) ms[li & 3] = -3.0;  // remove winner
  }

  double denom = 0.0;
#pragma unroll
  for (int r = 0; r < 8; ++r) denom += vals[r];
  if (denom < 1e-12) denom = 1e-12;

  const size_t base = (size_t)tok * 8;
#pragma unroll
  for (int r = 0; r < 8; ++r)
    if (lane == r) {
      out_w[base + r] = (float)(vals[r] / denom);
      out_i[base + r] = (float)idxs[r];
    }
}

extern "C" void kernel_launch(void* const* d_in, const int* in_sizes, int n_in,
                              void* d_out, int out_size, void* d_ws, size_t ws_size,
                              hipStream_t stream) {
  const float* hs = (const float*)d_in[0];  // [16384, 7168]
  const float* W  = (const float*)d_in[1];  // [256, 7168]
  float* out = (float*)d_out;
  // d_out layout: weights [T,8] | indices [T,8] | logits [T,256]
  float* out_w   = out;
  float* out_i   = out + (size_t)TOK * 8;
  float* logitsO = out + (size_t)TOK * 16;

  double* L64 = (double*)d_ws;  // [T, 256] f64 logit accumulators (33.5 MB)
  hipMemsetAsync(L64, 0, (size_t)TOK * NE * sizeof(double), stream);

  gemm_logits<<<dim3((TOK / BM) * (NE / BN) * NSPLIT), dim3(NTHR), 0, stream>>>(hs, W, L64);
  router<<<dim3(TOK * 64 / 256), dim3(256), 0, stream>>>(L64, out_w, out_i, logitsO);
}